// Round 11
// baseline (256.602 us; speedup 1.0000x reference)
//
#include <hip/hip_runtime.h>

typedef __bf16 bf16;
typedef __bf16 bf16x2 __attribute__((ext_vector_type(2)));
typedef __bf16 bf16x4 __attribute__((ext_vector_type(4)));
typedef __bf16 bf16x8 __attribute__((ext_vector_type(8)));
typedef float f32x4 __attribute__((ext_vector_type(4)));

#define TT_ 2048
#define CC_ 1024
#define HH_ 64

// scale * 1/ln(2): softmax via exp2, no max subtraction (|s|<~3, fp32-safe).
// Folded into q at projection time (qb is pre-scaled by qkv_kernel).
#define SCALE2 0.045084221f

static __device__ __forceinline__ unsigned pack_bf16(float a, float b) {
    union { bf16x2 h; unsigned u; } z;
    z.h = bf16x2{(bf16)a, (bf16)b};
    return z.u;
}
// v_permlane32_swap_b32: a' = [a.lo32 | b.lo32], b' = [a.hi32 | b.hi32]
static __device__ __forceinline__ void plswap32(unsigned &a, unsigned &b) {
    asm("v_permlane32_swap_b32 %0, %1" : "+v"(a), "+v"(b));
}
// v_permlane16_swap_b32: odd 16-rows of a swap with even 16-rows of b
static __device__ __forceinline__ void plswap16(unsigned &a, unsigned &b) {
    asm("v_permlane16_swap_b32 %0, %1" : "+v"(a), "+v"(b));
}

// ---------------- prep: Wt[m][n][k] = W_m[k][n], fp32 -> bf16, LDS transpose --
__global__ __launch_bounds__(256) void prep_w(const float* __restrict__ Wq,
                                              const float* __restrict__ Wk,
                                              const float* __restrict__ Wv,
                                              bf16* __restrict__ Wt) {
    __shared__ bf16 Ls[64 * 65];
    const int m  = blockIdx.x >> 4;
    const int k0 = (blockIdx.x & 15) * 64;
    const float* W = (m == 0) ? Wq : (m == 1) ? Wk : Wv;
    const int tid = threadIdx.x;
    #pragma unroll
    for (int j = 0; j < 4; ++j) {
        int idx = tid + 256 * j;
        int r   = idx >> 4;
        int c4  = (idx & 15) * 4;
        float4 w = *(const float4*)&W[(size_t)(k0 + r) * HH_ + c4];
        Ls[r * 65 + c4 + 0] = (bf16)w.x;
        Ls[r * 65 + c4 + 1] = (bf16)w.y;
        Ls[r * 65 + c4 + 2] = (bf16)w.z;
        Ls[r * 65 + c4 + 3] = (bf16)w.w;
    }
    __syncthreads();
    #pragma unroll
    for (int j = 0; j < 4; ++j) {
        int idx = tid + 256 * j;
        int n   = idx >> 4;
        int kc  = (idx & 15) * 4;
        bf16x4 v;
        #pragma unroll
        for (int i = 0; i < 4; ++i) v[i] = Ls[(kc + i) * 65 + n];
        *(bf16x4*)&Wt[m * 65536 + n * 1024 + k0 + kc] = v;
    }
}

// ---------------- fused QKV projection ---------------------------------------
// Round 11: r10's full-width swizzle (key = row&15) with the READ ADJACENCY
// BUG fixed. r10 read slots (s0, s0+1); with an odd key, (s0+1)^e != g+1 ->
// wrong data (NaN). Correct read: the two 16B halves of the fragment are
// INDEPENDENTLY addressed at LDS slots (g^e) and ((g+1)^e). Write side
// unchanged from r10 (involution permutation within each 256B row segment;
// staging coalescing preserved; rule #21 both-sides satisfied).
// Banking: e = lane -> s mod 8 = (quad*2)^(lane&7) uniform over all 8
// bank-groups, 2 lanes/bank = free (m136).
// Loop: issue glds(t+1, buf^1) -> ds_read+cvt+MFMA on buf -> __syncthreads
// (the only wait). 32-row tiles, grid 1024 = 4 blocks/CU, LDS 16.4 KB.
__global__ __launch_bounds__(256, 4) void qkv_kernel(const float* __restrict__ x,
                                                     const bf16* __restrict__ Wt,
                                                     bf16* __restrict__ qb,
                                                     bf16* __restrict__ kb,
                                                     bf16* __restrict__ vt) {
    __shared__ __align__(16) float XsF[2][32 * 64];
    const int tid  = threadIdx.x;
    const int wave = tid >> 6;
    const int wl   = tid & 63;
    const int lane = tid & 15;
    const int quad = wl >> 4;
    const int m0   = blockIdx.x * 32;

    // staging: wave w stages rows w*8..w*8+7; instr i covers 4 rows.
    // lane l -> row (l>>4), 16B slot (l&15); global slot pre-swizzled.
    const int rr = wl >> 4;
    const int sl = wl & 15;
    const float* gsrc[2];
    #pragma unroll
    for (int i = 0; i < 2; ++i) {
        int row = wave * 8 + i * 4 + rr;              // row in tile (0..31)
        int e   = row & 15;                           // full-width involution
        gsrc[i] = x + (size_t)(m0 + row) * CC_ + ((sl ^ e) << 2);
    }

    const bf16* wbase = Wt + (size_t)(wave * 48 + lane) * 1024 + quad * 8;

    f32x4 acc[2][3];
    #pragma unroll
    for (int i = 0; i < 2; ++i)
        #pragma unroll
        for (int j = 0; j < 3; ++j) acc[i][j] = f32x4{0.f, 0.f, 0.f, 0.f};

    // prologue: stage tile 0 into buf 0
    #pragma unroll
    for (int i = 0; i < 2; ++i)
        __builtin_amdgcn_global_load_lds(
            (const __attribute__((address_space(1))) void*)(gsrc[i]),
            (__attribute__((address_space(3))) void*)(&XsF[0][(wave * 8 + i * 4) * 64]),
            16, 0, 0);
    __syncthreads();

    for (int kbi = 0; kbi < 16; ++kbi) {
        const int cur = kbi & 1;
        const int k0  = kbi * 64;
        // issue next tile's async loads first (land during this tile's MFMAs)
        if (kbi < 15) {
            #pragma unroll
            for (int i = 0; i < 2; ++i)
                __builtin_amdgcn_global_load_lds(
                    (const __attribute__((address_space(1))) void*)(gsrc[i] + (kbi + 1) * 64),
                    (__attribute__((address_space(3))) void*)(&XsF[cur ^ 1][(wave * 8 + i * 4) * 64]),
                    16, 0, 0);
        }
        // A fragments: swizzled fp32 LDS reads (two independent b128) + cvt
        bf16x8 afr[2][2];
        #pragma unroll
        for (int step = 0; step < 2; ++step)
            #pragma unroll
            for (int rt = 0; rt < 2; ++rt) {
                int row = rt * 16 + lane;
                int e   = row & 15;                   // == lane
                int g   = step * 8 + quad * 2;        // target global slot
                float4 a = *(const float4*)&XsF[cur][row * 64 + ((g ^ e) << 2)];
                float4 b = *(const float4*)&XsF[cur][row * 64 + (((g + 1) ^ e) << 2)];
                afr[step][rt] = bf16x8{(bf16)a.x, (bf16)a.y, (bf16)a.z, (bf16)a.w,
                                       (bf16)b.x, (bf16)b.y, (bf16)b.z, (bf16)b.w};
            }
        // B fragments: Wt from L2
        bf16x8 bfr[2][3];
        #pragma unroll
        for (int step = 0; step < 2; ++step)
            #pragma unroll
            for (int ct = 0; ct < 3; ++ct)
                bfr[step][ct] = *(const bf16x8*)&wbase[(size_t)(ct * 16) * 1024 + k0 + step * 32];
        #pragma unroll
        for (int step = 0; step < 2; ++step)
            #pragma unroll
            for (int ct = 0; ct < 3; ++ct)
                #pragma unroll
                for (int rt = 0; rt < 2; ++rt)
                    acc[rt][ct] = __builtin_amdgcn_mfma_f32_16x16x32_bf16(afr[step][rt], bfr[step][ct], acc[rt][ct], 0, 0, 0);
        __syncthreads();   // vmcnt(0) drain (next tile landed) + wave sync
    }

    // epilogue: C/D layout col=lane, row=quad*4+r
    const int bb = m0 >> 11;
    const int t0 = m0 & 2047;
    bf16* Vb = (bf16*)&XsF[0][0];        // reuse buf0 (4.6 KB of 8 KB)
    #pragma unroll
    for (int ct = 0; ct < 3; ++ct) {
        int c0 = wave * 48 + ct * 16;
        if (c0 < 64) {                          // q: pre-scaled by SCALE2
            int h = c0 + lane;
            #pragma unroll
            for (int rt = 0; rt < 2; ++rt)
                #pragma unroll
                for (int r = 0; r < 4; ++r)
                    qb[(size_t)(m0 + rt * 16 + quad * 4 + r) * HH_ + h] = (bf16)(acc[rt][ct][r] * SCALE2);
        } else if (c0 < 128) {                  // k
            int h = (c0 - 64) + lane;
            #pragma unroll
            for (int rt = 0; rt < 2; ++rt)
                #pragma unroll
                for (int r = 0; r < 4; ++r)
                    kb[(size_t)(m0 + rt * 16 + quad * 4 + r) * HH_ + h] = (bf16)acc[rt][ct][r];
        } else {                                // v -> LDS for transpose
            int h = (c0 - 128) + lane;
            #pragma unroll
            for (int rt = 0; rt < 2; ++rt)
                #pragma unroll
                for (int r = 0; r < 4; ++r)
                    Vb[(rt * 16 + quad * 4 + r) * 72 + h] = (bf16)acc[rt][ct][r];
        }
    }
    __syncthreads();
    {
        int h  = tid >> 2;
        int tc = (tid & 3) * 8;
        bf16x8 v0;
        #pragma unroll
        for (int i = 0; i < 8; ++i) v0[i] = Vb[(tc + i) * 72 + h];
        *(bf16x8*)&vt[(size_t)bb * HH_ * TT_ + (size_t)h * TT_ + t0 + tc] = v0;
    }
}

// ---------------- flash attention, non-split, direct output ------------------
// Round-5 version (best total). One block per (bb, qi): grid 512, 2 blocks/CU.
// Balance: bb = j&15, p = j>>4, qi = (p<16) ? p : 47-p.
// Row-sums via a 5th MFMA with all-ones B; normalize in-register; fp32 out.
__global__ __launch_bounds__(256, 2) void attn_kernel(const bf16* __restrict__ qb,
                                                      const bf16* __restrict__ kb,
                                                      const bf16* __restrict__ vt,
                                                      float* __restrict__ out) {
    __shared__ __align__(16) bf16 Ks[128 * 72];
    __shared__ __align__(16) bf16 Vs[64 * 136];

    const int tid  = threadIdx.x;
    const int wave = tid >> 6;
    const int lane = tid & 15;
    const int quad = (tid & 63) >> 4;

    const int j  = blockIdx.x;
    const int bb = j & 15;
    const int p  = j >> 4;
    const int qi = (p < 16) ? p : 47 - p;
    const int nch = (qi >> 1) + 1;          // chunks of 128 keys, incl. diag

    const int qrow  = qi * 64 + wave * 16;
    const int qg    = qrow + lane;          // this lane's q row
    const int qmaxw = qrow + 15;            // max q row in this wave

    // staging assignments (per-thread constants)
    const int krow = tid >> 3, kc8 = (tid & 7) * 8;       // K: 128 x 64h
    const int vh   = tid >> 4, vc8 = (tid & 15) * 8;      // V^T: 64h x 128s
    const bf16* kp = kb + (size_t)(bb * TT_ + krow) * HH_ + kc8;
    const bf16* vp = vt + (size_t)bb * HH_ * TT_ + (size_t)vh * TT_ + vc8;

    // prologue: issue chunk-0 loads
    bf16x8 kr[4], vvr[4];
    #pragma unroll
    for (int j2 = 0; j2 < 4; ++j2) kr[j2]  = *(const bf16x8*)&kp[(size_t)j2 * 32 * HH_];
    #pragma unroll
    for (int j2 = 0; j2 < 4; ++j2) vvr[j2] = *(const bf16x8*)&vp[j2 * 16 * TT_];

    // Q fragment (B operand): lane -> q col, quad*8 -> h  (pre-scaled)
    bf16x8 aq[2];
    #pragma unroll
    for (int step = 0; step < 2; ++step)
        aq[step] = *(const bf16x8*)&qb[(size_t)(bb * TT_ + qg) * HH_ + step * 32 + quad * 8];

    // all-ones B fragment for the row-sum MFMA
    bf16x8 vones;
    #pragma unroll
    for (int i = 0; i < 8; ++i) vones[i] = (bf16)1.0f;

    f32x4 o_acc[4];
    #pragma unroll
    for (int ht = 0; ht < 4; ++ht) o_acc[ht] = f32x4{0.f, 0.f, 0.f, 0.f};
    f32x4 lacc = f32x4{0.f, 0.f, 0.f, 0.f};

    for (int c = 0; c < nch; ++c) {
        const int s0 = c * 128;
        __syncthreads();                 // all waves done computing chunk c-1
        #pragma unroll
        for (int j2 = 0; j2 < 4; ++j2) *(bf16x8*)&Ks[(krow + 32 * j2) * 72 + kc8] = kr[j2];
        #pragma unroll
        for (int j2 = 0; j2 < 4; ++j2) *(bf16x8*)&Vs[(vh + 16 * j2) * 136 + vc8]  = vvr[j2];
        __syncthreads();
        if (c + 1 < nch) {               // issue next chunk's loads early
            #pragma unroll
            for (int j2 = 0; j2 < 4; ++j2)
                kr[j2] = *(const bf16x8*)&kp[(size_t)((c + 1) * 128 + j2 * 32) * HH_];
            #pragma unroll
            for (int j2 = 0; j2 < 4; ++j2)
                vvr[j2] = *(const bf16x8*)&vp[(c + 1) * 128 + j2 * 16 * TT_];
        }

        const bool msk = (c == nch - 1);
        #pragma unroll
        for (int w = 0; w < 4; ++w) {       // 4 windows of 32 keys
            if (msk && (s0 + w * 32 > qmaxw)) continue;       // wave-uniform
            const bool haveB = !msk || (s0 + w * 32 + 16 <= qmaxw);

            // QK^T (swapped): s[key=tile+quad*4+r][q=qg]
            f32x4 sA = {0.f, 0.f, 0.f, 0.f};
            f32x4 sB = {0.f, 0.f, 0.f, 0.f};
            __builtin_amdgcn_s_setprio(1);
            {
                bf16x8 ak0 = *(const bf16x8*)&Ks[(w * 32 + lane) * 72 + quad * 8];
                bf16x8 ak1 = *(const bf16x8*)&Ks[(w * 32 + lane) * 72 + 32 + quad * 8];
                sA = __builtin_amdgcn_mfma_f32_16x16x32_bf16(ak0, aq[0], sA, 0, 0, 0);
                sA = __builtin_amdgcn_mfma_f32_16x16x32_bf16(ak1, aq[1], sA, 0, 0, 0);
            }
            if (haveB) {
                bf16x8 bk0 = *(const bf16x8*)&Ks[(w * 32 + 16 + lane) * 72 + quad * 8];
                bf16x8 bk1 = *(const bf16x8*)&Ks[(w * 32 + 16 + lane) * 72 + 32 + quad * 8];
                sB = __builtin_amdgcn_mfma_f32_16x16x32_bf16(bk0, aq[0], sB, 0, 0, 0);
                sB = __builtin_amdgcn_mfma_f32_16x16x32_bf16(bk1, aq[1], sB, 0, 0, 0);
            }
            __builtin_amdgcn_s_setprio(0);

            // softmax (in-register, max-free; scale pre-folded into q)
            const int kA0 = s0 + w * 32 + quad * 4;
            float eA[4], eB[4];
            #pragma unroll
            for (int r = 0; r < 4; ++r) {
                float e = __builtin_amdgcn_exp2f(sA[r]);
                if (msk && (kA0 + r > qg)) e = 0.f;
                eA[r] = e;
            }
            if (haveB) {
                #pragma unroll
                for (int r = 0; r < 4; ++r) {
                    float e = __builtin_amdgcn_exp2f(sB[r]);
                    if (msk && (kA0 + 16 + r > qg)) e = 0.f;
                    eB[r] = e;
                }
            } else {
                #pragma unroll
                for (int r = 0; r < 4; ++r) eB[r] = 0.f;
            }

            // P: C-layout -> 16x16x32 A-layout, all in registers
            unsigned d0 = pack_bf16(eA[0], eA[1]);
            unsigned d1 = pack_bf16(eA[2], eA[3]);
            unsigned d2 = pack_bf16(eB[0], eB[1]);
            unsigned d3 = pack_bf16(eB[2], eB[3]);
            plswap32(d0, d2);
            plswap16(d0, d2);
            plswap32(d1, d3);
            plswap16(d1, d3);
            union { unsigned u[4]; bf16x8 v; } apu;
            apu.u[0] = d0; apu.u[1] = d1; apu.u[2] = d2; apu.u[3] = d3;

            // PV + row-sum: x32 MFMA straight from registers + Vs
            __builtin_amdgcn_s_setprio(1);
            #pragma unroll
            for (int ht = 0; ht < 4; ++ht) {
                bf16x8 bv = *(const bf16x8*)&Vs[(ht * 16 + lane) * 136 + w * 32 + quad * 8];
                o_acc[ht] = __builtin_amdgcn_mfma_f32_16x16x32_bf16(apu.v, bv, o_acc[ht], 0, 0, 0);
            }
            lacc = __builtin_amdgcn_mfma_f32_16x16x32_bf16(apu.v, vones, lacc, 0, 0, 0);
            __builtin_amdgcn_s_setprio(0);
        }
    }

    // epilogue: normalize and write fp32 output directly.
    // o_acc[ht][r]: row q = qrow + quad*4 + r, col h = ht*16 + lane.
    // lacc[r] = rowsum for the SAME q (all 16 cols identical).
    float inv[4];
    #pragma unroll
    for (int r = 0; r < 4; ++r) inv[r] = __builtin_amdgcn_rcpf(lacc[r]);
    #pragma unroll
    for (int ht = 0; ht < 4; ++ht)
        #pragma unroll
        for (int r = 0; r < 4; ++r)
            out[(size_t)(bb * TT_ + qrow + quad * 4 + r) * HH_ + ht * 16 + lane] = o_acc[ht][r] * inv[r];
}

extern "C" void kernel_launch(void* const* d_in, const int* in_sizes, int n_in,
                              void* d_out, int out_size, void* d_ws, size_t ws_size,
                              hipStream_t stream) {
    const float* x  = (const float*)d_in[0];
    const float* Wq = (const float*)d_in[1];
    const float* Wk = (const float*)d_in[2];
    const float* Wv = (const float*)d_in[3];
    float* out = (float*)d_out;

    char* ws = (char*)d_ws;
    bf16*  qb = (bf16*)(ws);                       // 4 MiB (pre-scaled q)
    bf16*  kb = (bf16*)(ws + 4194304);             // 4 MiB
    bf16*  vt = (bf16*)(ws + 8388608);             // 4 MiB  V^T [bb][h][t]
    bf16*  Wt = (bf16*)(ws + 12582912);            // 384 KiB

    prep_w<<<48, 256, 0, stream>>>(Wq, Wk, Wv, Wt);
    qkv_kernel<<<1024, 256, 0, stream>>>(x, Wt, qb, kb, vt);
    attn_kernel<<<512, 256, 0, stream>>>(qb, kb, vt, out);
}

// Round 12
// 238.525 us; speedup vs baseline: 1.0758x; 1.0758x over previous
//
#include <hip/hip_runtime.h>

typedef __bf16 bf16;
typedef __bf16 bf16x2 __attribute__((ext_vector_type(2)));
typedef __bf16 bf16x4 __attribute__((ext_vector_type(4)));
typedef __bf16 bf16x8 __attribute__((ext_vector_type(8)));
typedef float f32x4 __attribute__((ext_vector_type(4)));

#define TT_ 2048
#define CC_ 1024
#define HH_ 64

// scale * 1/ln(2): softmax via exp2, no max subtraction (|s|<~3, fp32-safe).
// Folded into q at projection time (qb is pre-scaled by qkv_kernel).
#define SCALE2 0.045084221f

static __device__ __forceinline__ unsigned pack_bf16(float a, float b) {
    union { bf16x2 h; unsigned u; } z;
    z.h = bf16x2{(bf16)a, (bf16)b};
    return z.u;
}
// v_permlane32_swap_b32: a' = [a.lo32 | b.lo32], b' = [a.hi32 | b.hi32]
static __device__ __forceinline__ void plswap32(unsigned &a, unsigned &b) {
    asm("v_permlane32_swap_b32 %0, %1" : "+v"(a), "+v"(b));
}
// v_permlane16_swap_b32: odd 16-rows of a swap with even 16-rows of b
static __device__ __forceinline__ void plswap16(unsigned &a, unsigned &b) {
    asm("v_permlane16_swap_b32 %0, %1" : "+v"(a), "+v"(b));
}

// ---------------- prep: Wt[m][n][k] = W_m[k][n], fp32 -> bf16, LDS transpose --
__global__ __launch_bounds__(256) void prep_w(const float* __restrict__ Wq,
                                              const float* __restrict__ Wk,
                                              const float* __restrict__ Wv,
                                              bf16* __restrict__ Wt) {
    __shared__ bf16 Ls[64 * 65];
    const int m  = blockIdx.x >> 4;
    const int k0 = (blockIdx.x & 15) * 64;
    const float* W = (m == 0) ? Wq : (m == 1) ? Wk : Wv;
    const int tid = threadIdx.x;
    #pragma unroll
    for (int j = 0; j < 4; ++j) {
        int idx = tid + 256 * j;
        int r   = idx >> 4;
        int c4  = (idx & 15) * 4;
        float4 w = *(const float4*)&W[(size_t)(k0 + r) * HH_ + c4];
        Ls[r * 65 + c4 + 0] = (bf16)w.x;
        Ls[r * 65 + c4 + 1] = (bf16)w.y;
        Ls[r * 65 + c4 + 2] = (bf16)w.z;
        Ls[r * 65 + c4 + 3] = (bf16)w.w;
    }
    __syncthreads();
    #pragma unroll
    for (int j = 0; j < 4; ++j) {
        int idx = tid + 256 * j;
        int n   = idx >> 4;
        int kc  = (idx & 15) * 4;
        bf16x4 v;
        #pragma unroll
        for (int i = 0; i < 4; ++i) v[i] = Ls[(kc + i) * 65 + n];
        *(bf16x4*)&Wt[m * 65536 + n * 1024 + k0 + kc] = v;
    }
}

// ---------------- fused QKV projection (r5 verbatim -- best measured) --------
// 64-row tiles (24 MFMA per staged fragment-set), deep pipeline: x distance-2
// (xS0/xS1), Wt distance-1 (bfrA/bfrB), unroll-by-2 macro. q PRE-SCALED.
#define QKV_STEP(KBI, BU, BP, XLD, XWR)                                        \
    {                                                                          \
        const int k0 = (KBI) * 64;                                             \
        __syncthreads();                                                       \
        if ((KBI) < 14) {                                                      \
            _Pragma("unroll")                                                  \
            for (int rr = 0; rr < 4; ++rr)                                     \
                XLD[rr] = *(const float4*)&x[(size_t)(m0 + srow + rr * 16) * CC_ + k0 + 128 + scol]; \
        }                                                                      \
        if ((KBI) < 15) {                                                      \
            _Pragma("unroll")                                                  \
            for (int step = 0; step < 2; ++step)                               \
                _Pragma("unroll")                                              \
                for (int ct = 0; ct < 3; ++ct)                                 \
                    BP[step][ct] = *(const bf16x8*)&Wt[(size_t)(wave * 48 + ct * 16 + lane) * 1024 + k0 + 64 + step * 32 + quad * 8]; \
        }                                                                      \
        bf16x8 afr[2][4];                                                      \
        _Pragma("unroll")                                                      \
        for (int step = 0; step < 2; ++step)                                   \
            _Pragma("unroll")                                                  \
            for (int rt = 0; rt < 4; ++rt)                                     \
                afr[step][rt] = *(const bf16x8*)&Xs[(KBI) & 1][(rt * 16 + lane) * 72 + step * 32 + quad * 8]; \
        _Pragma("unroll")                                                      \
        for (int step = 0; step < 2; ++step)                                   \
            _Pragma("unroll")                                                  \
            for (int ct = 0; ct < 3; ++ct)                                     \
                _Pragma("unroll")                                              \
                for (int rt = 0; rt < 4; ++rt)                                 \
                    acc[rt][ct] = __builtin_amdgcn_mfma_f32_16x16x32_bf16(afr[step][rt], BU[step][ct], acc[rt][ct], 0, 0, 0); \
        if ((KBI) < 15) {                                                      \
            _Pragma("unroll")                                                  \
            for (int rr = 0; rr < 4; ++rr) {                                   \
                bf16x4 bv = {(bf16)XWR[rr].x, (bf16)XWR[rr].y, (bf16)XWR[rr].z, (bf16)XWR[rr].w}; \
                *(bf16x4*)&Xs[((KBI) + 1) & 1][(srow + rr * 16) * 72 + scol] = bv; \
            }                                                                  \
        }                                                                      \
    }

__global__ __launch_bounds__(256, 2) void qkv_kernel(const float* __restrict__ x,
                                                     const bf16* __restrict__ Wt,
                                                     bf16* __restrict__ qb,
                                                     bf16* __restrict__ kb,
                                                     bf16* __restrict__ vt) {
    __shared__ __align__(16) bf16 Xs[2][64 * 72];
    const int tid  = threadIdx.x;
    const int wave = tid >> 6;
    const int lane = tid & 15;
    const int quad = (tid & 63) >> 4;
    const int m0   = blockIdx.x * 64;

    f32x4 acc[4][3];
    #pragma unroll
    for (int i = 0; i < 4; ++i)
        #pragma unroll
        for (int j = 0; j < 3; ++j) acc[i][j] = f32x4{0.f, 0.f, 0.f, 0.f};

    const int srow = tid >> 4;
    const int scol = (tid & 15) * 4;

    // prologue: tile0 -> Xs[0] directly; issue tile1 into xS1; issue Wt tile0.
    {
        float4 x0[4];
        #pragma unroll
        for (int rr = 0; rr < 4; ++rr)
            x0[rr] = *(const float4*)&x[(size_t)(m0 + srow + rr * 16) * CC_ + scol];
        #pragma unroll
        for (int rr = 0; rr < 4; ++rr) {
            bf16x4 bv = {(bf16)x0[rr].x, (bf16)x0[rr].y, (bf16)x0[rr].z, (bf16)x0[rr].w};
            *(bf16x4*)&Xs[0][(srow + rr * 16) * 72 + scol] = bv;
        }
    }
    float4 xS0[4], xS1[4];
    #pragma unroll
    for (int rr = 0; rr < 4; ++rr)
        xS1[rr] = *(const float4*)&x[(size_t)(m0 + srow + rr * 16) * CC_ + 64 + scol];
    bf16x8 bfrA[2][3], bfrB[2][3];
    #pragma unroll
    for (int step = 0; step < 2; ++step)
        #pragma unroll
        for (int ct = 0; ct < 3; ++ct)
            bfrA[step][ct] = *(const bf16x8*)&Wt[(size_t)(wave * 48 + ct * 16 + lane) * 1024 + step * 32 + quad * 8];

    for (int kb2 = 0; kb2 < 16; kb2 += 2) {
        QKV_STEP(kb2,     bfrA, bfrB, xS0, xS1)
        QKV_STEP(kb2 + 1, bfrB, bfrA, xS1, xS0)
    }

    // epilogue: C/D layout col=lane, row=quad*4+r
    const int bb = m0 >> 11;
    const int t0 = m0 & 2047;
    __syncthreads();
    #pragma unroll
    for (int ct = 0; ct < 3; ++ct) {
        int c0 = wave * 48 + ct * 16;
        if (c0 < 64) {                          // q: pre-scaled by SCALE2
            int h = c0 + lane;
            #pragma unroll
            for (int rt = 0; rt < 4; ++rt)
                #pragma unroll
                for (int r = 0; r < 4; ++r)
                    qb[(size_t)(m0 + rt * 16 + quad * 4 + r) * HH_ + h] = (bf16)(acc[rt][ct][r] * SCALE2);
        } else if (c0 < 128) {                  // k
            int h = (c0 - 64) + lane;
            #pragma unroll
            for (int rt = 0; rt < 4; ++rt)
                #pragma unroll
                for (int r = 0; r < 4; ++r)
                    kb[(size_t)(m0 + rt * 16 + quad * 4 + r) * HH_ + h] = (bf16)acc[rt][ct][r];
        } else {                                // v -> LDS for transpose
            int h = (c0 - 128) + lane;
            #pragma unroll
            for (int rt = 0; rt < 4; ++rt)
                #pragma unroll
                for (int r = 0; r < 4; ++r)
                    Xs[0][(rt * 16 + quad * 4 + r) * 72 + h] = (bf16)acc[rt][ct][r];
        }
    }
    __syncthreads();
    {
        int h  = tid >> 2;
        int tc = (tid & 3) * 16;
        bf16x8 v0, v1;
        #pragma unroll
        for (int i = 0; i < 8; ++i) v0[i] = Xs[0][(tc + i) * 72 + h];
        #pragma unroll
        for (int i = 0; i < 8; ++i) v1[i] = Xs[0][(tc + 8 + i) * 72 + h];
        bf16* dst = &vt[(size_t)bb * HH_ * TT_ + (size_t)h * TT_ + t0 + tc];
        *(bf16x8*)dst = v0;
        *(bf16x8*)(dst + 8) = v1;
    }
}

// ---------------- flash attention, non-split, direct output ------------------
// Round 12: r5 structure + ONE barrier per chunk via LDS double-buffering.
// Iter c: issue loads(c+1) -> compute on buf[c&1] -> ds_write buf[(c+1)&1]
// -> barrier. Safety: writes of buf^1 in iter c are separated from reads of
// the same buffer (iter c-1) by iter c-1's barrier, and from iter c+1's
// reads by iter c's barrier. Chunk-(c+1) global loads stay in flight across
// the WHOLE compute phase. LDS 70 KB -> still 2 blocks/CU (140 < 160 KB).
__global__ __launch_bounds__(256, 2) void attn_kernel(const bf16* __restrict__ qb,
                                                      const bf16* __restrict__ kb,
                                                      const bf16* __restrict__ vt,
                                                      float* __restrict__ out) {
    __shared__ __align__(16) bf16 Ks[2][128 * 72];
    __shared__ __align__(16) bf16 Vs[2][64 * 136];

    const int tid  = threadIdx.x;
    const int wave = tid >> 6;
    const int lane = tid & 15;
    const int quad = (tid & 63) >> 4;

    const int j  = blockIdx.x;
    const int bb = j & 15;
    const int p  = j >> 4;
    const int qi = (p < 16) ? p : 47 - p;
    const int nch = (qi >> 1) + 1;          // chunks of 128 keys, incl. diag

    const int qrow  = qi * 64 + wave * 16;
    const int qg    = qrow + lane;          // this lane's q row
    const int qmaxw = qrow + 15;            // max q row in this wave

    // staging assignments (per-thread constants)
    const int krow = tid >> 3, kc8 = (tid & 7) * 8;       // K: 128 x 64h
    const int vh   = tid >> 4, vc8 = (tid & 15) * 8;      // V^T: 64h x 128s
    const bf16* kp = kb + (size_t)(bb * TT_ + krow) * HH_ + kc8;
    const bf16* vp = vt + (size_t)bb * HH_ * TT_ + (size_t)vh * TT_ + vc8;

    // prologue: chunk-0 into buf 0
    bf16x8 kr[4], vvr[4];
    #pragma unroll
    for (int j2 = 0; j2 < 4; ++j2) kr[j2]  = *(const bf16x8*)&kp[(size_t)j2 * 32 * HH_];
    #pragma unroll
    for (int j2 = 0; j2 < 4; ++j2) vvr[j2] = *(const bf16x8*)&vp[j2 * 16 * TT_];
    #pragma unroll
    for (int j2 = 0; j2 < 4; ++j2) *(bf16x8*)&Ks[0][(krow + 32 * j2) * 72 + kc8] = kr[j2];
    #pragma unroll
    for (int j2 = 0; j2 < 4; ++j2) *(bf16x8*)&Vs[0][(vh + 16 * j2) * 136 + vc8]  = vvr[j2];
    __syncthreads();

    // Q fragment (B operand): lane -> q col, quad*8 -> h  (pre-scaled)
    bf16x8 aq[2];
    #pragma unroll
    for (int step = 0; step < 2; ++step)
        aq[step] = *(const bf16x8*)&qb[(size_t)(bb * TT_ + qg) * HH_ + step * 32 + quad * 8];

    // all-ones B fragment for the row-sum MFMA
    bf16x8 vones;
    #pragma unroll
    for (int i = 0; i < 8; ++i) vones[i] = (bf16)1.0f;

    f32x4 o_acc[4];
    #pragma unroll
    for (int ht = 0; ht < 4; ++ht) o_acc[ht] = f32x4{0.f, 0.f, 0.f, 0.f};
    f32x4 lacc = f32x4{0.f, 0.f, 0.f, 0.f};

    for (int c = 0; c < nch; ++c) {
        const int s0  = c * 128;
        const int cur = c & 1;
        // issue next chunk's loads first -- in flight across all of compute
        if (c + 1 < nch) {
            #pragma unroll
            for (int j2 = 0; j2 < 4; ++j2)
                kr[j2] = *(const bf16x8*)&kp[(size_t)((c + 1) * 128 + j2 * 32) * HH_];
            #pragma unroll
            for (int j2 = 0; j2 < 4; ++j2)
                vvr[j2] = *(const bf16x8*)&vp[(c + 1) * 128 + j2 * 16 * TT_];
        }

        const bool msk = (c == nch - 1);
        #pragma unroll
        for (int w = 0; w < 4; ++w) {       // 4 windows of 32 keys
            if (msk && (s0 + w * 32 > qmaxw)) continue;       // wave-uniform
            const bool haveB = !msk || (s0 + w * 32 + 16 <= qmaxw);

            // QK^T (swapped): s[key=tile+quad*4+r][q=qg]
            f32x4 sA = {0.f, 0.f, 0.f, 0.f};
            f32x4 sB = {0.f, 0.f, 0.f, 0.f};
            __builtin_amdgcn_s_setprio(1);
            {
                bf16x8 ak0 = *(const bf16x8*)&Ks[cur][(w * 32 + lane) * 72 + quad * 8];
                bf16x8 ak1 = *(const bf16x8*)&Ks[cur][(w * 32 + lane) * 72 + 32 + quad * 8];
                sA = __builtin_amdgcn_mfma_f32_16x16x32_bf16(ak0, aq[0], sA, 0, 0, 0);
                sA = __builtin_amdgcn_mfma_f32_16x16x32_bf16(ak1, aq[1], sA, 0, 0, 0);
            }
            if (haveB) {
                bf16x8 bk0 = *(const bf16x8*)&Ks[cur][(w * 32 + 16 + lane) * 72 + quad * 8];
                bf16x8 bk1 = *(const bf16x8*)&Ks[cur][(w * 32 + 16 + lane) * 72 + 32 + quad * 8];
                sB = __builtin_amdgcn_mfma_f32_16x16x32_bf16(bk0, aq[0], sB, 0, 0, 0);
                sB = __builtin_amdgcn_mfma_f32_16x16x32_bf16(bk1, aq[1], sB, 0, 0, 0);
            }
            __builtin_amdgcn_s_setprio(0);

            // softmax (in-register, max-free; scale pre-folded into q)
            const int kA0 = s0 + w * 32 + quad * 4;
            float eA[4], eB[4];
            #pragma unroll
            for (int r = 0; r < 4; ++r) {
                float e = __builtin_amdgcn_exp2f(sA[r]);
                if (msk && (kA0 + r > qg)) e = 0.f;
                eA[r] = e;
            }
            if (haveB) {
                #pragma unroll
                for (int r = 0; r < 4; ++r) {
                    float e = __builtin_amdgcn_exp2f(sB[r]);
                    if (msk && (kA0 + 16 + r > qg)) e = 0.f;
                    eB[r] = e;
                }
            } else {
                #pragma unroll
                for (int r = 0; r < 4; ++r) eB[r] = 0.f;
            }

            // P: C-layout -> 16x16x32 A-layout, all in registers
            unsigned d0 = pack_bf16(eA[0], eA[1]);
            unsigned d1 = pack_bf16(eA[2], eA[3]);
            unsigned d2 = pack_bf16(eB[0], eB[1]);
            unsigned d3 = pack_bf16(eB[2], eB[3]);
            plswap32(d0, d2);
            plswap16(d0, d2);
            plswap32(d1, d3);
            plswap16(d1, d3);
            union { unsigned u[4]; bf16x8 v; } apu;
            apu.u[0] = d0; apu.u[1] = d1; apu.u[2] = d2; apu.u[3] = d3;

            // PV + row-sum: x32 MFMA straight from registers + Vs
            __builtin_amdgcn_s_setprio(1);
            #pragma unroll
            for (int ht = 0; ht < 4; ++ht) {
                bf16x8 bv = *(const bf16x8*)&Vs[cur][(ht * 16 + lane) * 136 + w * 32 + quad * 8];
                o_acc[ht] = __builtin_amdgcn_mfma_f32_16x16x32_bf16(apu.v, bv, o_acc[ht], 0, 0, 0);
            }
            lacc = __builtin_amdgcn_mfma_f32_16x16x32_bf16(apu.v, vones, lacc, 0, 0, 0);
            __builtin_amdgcn_s_setprio(0);
        }

        // write next chunk into the other buffer; ONE barrier per chunk
        if (c + 1 < nch) {
            #pragma unroll
            for (int j2 = 0; j2 < 4; ++j2) *(bf16x8*)&Ks[cur ^ 1][(krow + 32 * j2) * 72 + kc8] = kr[j2];
            #pragma unroll
            for (int j2 = 0; j2 < 4; ++j2) *(bf16x8*)&Vs[cur ^ 1][(vh + 16 * j2) * 136 + vc8]  = vvr[j2];
            __syncthreads();
        }
    }

    // epilogue: normalize and write fp32 output directly.
    // o_acc[ht][r]: row q = qrow + quad*4 + r, col h = ht*16 + lane.
    // lacc[r] = rowsum for the SAME q (all 16 cols identical).
    float inv[4];
    #pragma unroll
    for (int r = 0; r < 4; ++r) inv[r] = __builtin_amdgcn_rcpf(lacc[r]);
    #pragma unroll
    for (int ht = 0; ht < 4; ++ht)
        #pragma unroll
        for (int r = 0; r < 4; ++r)
            out[(size_t)(bb * TT_ + qrow + quad * 4 + r) * HH_ + ht * 16 + lane] = o_acc[ht][r] * inv[r];
}

extern "C" void kernel_launch(void* const* d_in, const int* in_sizes, int n_in,
                              void* d_out, int out_size, void* d_ws, size_t ws_size,
                              hipStream_t stream) {
    const float* x  = (const float*)d_in[0];
    const float* Wq = (const float*)d_in[1];
    const float* Wk = (const float*)d_in[2];
    const float* Wv = (const float*)d_in[3];
    float* out = (float*)d_out;

    char* ws = (char*)d_ws;
    bf16*  qb = (bf16*)(ws);                       // 4 MiB (pre-scaled q)
    bf16*  kb = (bf16*)(ws + 4194304);             // 4 MiB
    bf16*  vt = (bf16*)(ws + 8388608);             // 4 MiB  V^T [bb][h][t]
    bf16*  Wt = (bf16*)(ws + 12582912);            // 384 KiB

    prep_w<<<48, 256, 0, stream>>>(Wq, Wk, Wv, Wt);
    qkv_kernel<<<512, 256, 0, stream>>>(x, Wt, qb, kb, vt);
    attn_kernel<<<512, 256, 0, stream>>>(qb, kb, vt, out);
}

// Round 13
// 232.063 us; speedup vs baseline: 1.1057x; 1.0278x over previous
//
#include <hip/hip_runtime.h>

typedef __bf16 bf16;
typedef __bf16 bf16x2 __attribute__((ext_vector_type(2)));
typedef __bf16 bf16x4 __attribute__((ext_vector_type(4)));
typedef __bf16 bf16x8 __attribute__((ext_vector_type(8)));
typedef float f32x4 __attribute__((ext_vector_type(4)));

#define TT_ 2048
#define CC_ 1024
#define HH_ 64

// scale * 1/ln(2): softmax via exp2, no max subtraction (|s|<~3, fp32-safe).
// Folded into q at projection time (qb is pre-scaled by qkv_kernel).
#define SCALE2 0.045084221f

static __device__ __forceinline__ unsigned pack_bf16(float a, float b) {
    union { bf16x2 h; unsigned u; } z;
    z.h = bf16x2{(bf16)a, (bf16)b};
    return z.u;
}
// v_permlane32_swap_b32: a' = [a.lo32 | b.lo32], b' = [a.hi32 | b.hi32]
static __device__ __forceinline__ void plswap32(unsigned &a, unsigned &b) {
    asm("v_permlane32_swap_b32 %0, %1" : "+v"(a), "+v"(b));
}
// v_permlane16_swap_b32: odd 16-rows of a swap with even 16-rows of b
static __device__ __forceinline__ void plswap16(unsigned &a, unsigned &b) {
    asm("v_permlane16_swap_b32 %0, %1" : "+v"(a), "+v"(b));
}

// ---------------- prep: Wt[m][n][k] = W_m[k][n], fp32 -> bf16, LDS transpose --
__global__ __launch_bounds__(256) void prep_w(const float* __restrict__ Wq,
                                              const float* __restrict__ Wk,
                                              const float* __restrict__ Wv,
                                              bf16* __restrict__ Wt) {
    __shared__ bf16 Ls[64 * 65];
    const int m  = blockIdx.x >> 4;
    const int k0 = (blockIdx.x & 15) * 64;
    const float* W = (m == 0) ? Wq : (m == 1) ? Wk : Wv;
    const int tid = threadIdx.x;
    #pragma unroll
    for (int j = 0; j < 4; ++j) {
        int idx = tid + 256 * j;
        int r   = idx >> 4;
        int c4  = (idx & 15) * 4;
        float4 w = *(const float4*)&W[(size_t)(k0 + r) * HH_ + c4];
        Ls[r * 65 + c4 + 0] = (bf16)w.x;
        Ls[r * 65 + c4 + 1] = (bf16)w.y;
        Ls[r * 65 + c4 + 2] = (bf16)w.z;
        Ls[r * 65 + c4 + 3] = (bf16)w.w;
    }
    __syncthreads();
    #pragma unroll
    for (int j = 0; j < 4; ++j) {
        int idx = tid + 256 * j;
        int n   = idx >> 4;
        int kc  = (idx & 15) * 4;
        bf16x4 v;
        #pragma unroll
        for (int i = 0; i < 4; ++i) v[i] = Ls[(kc + i) * 65 + n];
        *(bf16x4*)&Wt[m * 65536 + n * 1024 + k0 + kc] = v;
    }
}

// ---------------- fused QKV projection (r5 verbatim -- best measured) --------
#define QKV_STEP(KBI, BU, BP, XLD, XWR)                                        \
    {                                                                          \
        const int k0 = (KBI) * 64;                                             \
        __syncthreads();                                                       \
        if ((KBI) < 14) {                                                      \
            _Pragma("unroll")                                                  \
            for (int rr = 0; rr < 4; ++rr)                                     \
                XLD[rr] = *(const float4*)&x[(size_t)(m0 + srow + rr * 16) * CC_ + k0 + 128 + scol]; \
        }                                                                      \
        if ((KBI) < 15) {                                                      \
            _Pragma("unroll")                                                  \
            for (int step = 0; step < 2; ++step)                               \
                _Pragma("unroll")                                              \
                for (int ct = 0; ct < 3; ++ct)                                 \
                    BP[step][ct] = *(const bf16x8*)&Wt[(size_t)(wave * 48 + ct * 16 + lane) * 1024 + k0 + 64 + step * 32 + quad * 8]; \
        }                                                                      \
        bf16x8 afr[2][4];                                                      \
        _Pragma("unroll")                                                      \
        for (int step = 0; step < 2; ++step)                                   \
            _Pragma("unroll")                                                  \
            for (int rt = 0; rt < 4; ++rt)                                     \
                afr[step][rt] = *(const bf16x8*)&Xs[(KBI) & 1][(rt * 16 + lane) * 72 + step * 32 + quad * 8]; \
        _Pragma("unroll")                                                      \
        for (int step = 0; step < 2; ++step)                                   \
            _Pragma("unroll")                                                  \
            for (int ct = 0; ct < 3; ++ct)                                     \
                _Pragma("unroll")                                              \
                for (int rt = 0; rt < 4; ++rt)                                 \
                    acc[rt][ct] = __builtin_amdgcn_mfma_f32_16x16x32_bf16(afr[step][rt], BU[step][ct], acc[rt][ct], 0, 0, 0); \
        if ((KBI) < 15) {                                                      \
            _Pragma("unroll")                                                  \
            for (int rr = 0; rr < 4; ++rr) {                                   \
                bf16x4 bv = {(bf16)XWR[rr].x, (bf16)XWR[rr].y, (bf16)XWR[rr].z, (bf16)XWR[rr].w}; \
                *(bf16x4*)&Xs[((KBI) + 1) & 1][(srow + rr * 16) * 72 + scol] = bv; \
            }                                                                  \
        }                                                                      \
    }

__global__ __launch_bounds__(256, 2) void qkv_kernel(const float* __restrict__ x,
                                                     const bf16* __restrict__ Wt,
                                                     bf16* __restrict__ qb,
                                                     bf16* __restrict__ kb,
                                                     bf16* __restrict__ vt) {
    __shared__ __align__(16) bf16 Xs[2][64 * 72];
    const int tid  = threadIdx.x;
    const int wave = tid >> 6;
    const int lane = tid & 15;
    const int quad = (tid & 63) >> 4;
    const int m0   = blockIdx.x * 64;

    f32x4 acc[4][3];
    #pragma unroll
    for (int i = 0; i < 4; ++i)
        #pragma unroll
        for (int j = 0; j < 3; ++j) acc[i][j] = f32x4{0.f, 0.f, 0.f, 0.f};

    const int srow = tid >> 4;
    const int scol = (tid & 15) * 4;

    // prologue: tile0 -> Xs[0] directly; issue tile1 into xS1; issue Wt tile0.
    {
        float4 x0[4];
        #pragma unroll
        for (int rr = 0; rr < 4; ++rr)
            x0[rr] = *(const float4*)&x[(size_t)(m0 + srow + rr * 16) * CC_ + scol];
        #pragma unroll
        for (int rr = 0; rr < 4; ++rr) {
            bf16x4 bv = {(bf16)x0[rr].x, (bf16)x0[rr].y, (bf16)x0[rr].z, (bf16)x0[rr].w};
            *(bf16x4*)&Xs[0][(srow + rr * 16) * 72 + scol] = bv;
        }
    }
    float4 xS0[4], xS1[4];
    #pragma unroll
    for (int rr = 0; rr < 4; ++rr)
        xS1[rr] = *(const float4*)&x[(size_t)(m0 + srow + rr * 16) * CC_ + 64 + scol];
    bf16x8 bfrA[2][3], bfrB[2][3];
    #pragma unroll
    for (int step = 0; step < 2; ++step)
        #pragma unroll
        for (int ct = 0; ct < 3; ++ct)
            bfrA[step][ct] = *(const bf16x8*)&Wt[(size_t)(wave * 48 + ct * 16 + lane) * 1024 + step * 32 + quad * 8];

    for (int kb2 = 0; kb2 < 16; kb2 += 2) {
        QKV_STEP(kb2,     bfrA, bfrB, xS0, xS1)
        QKV_STEP(kb2 + 1, bfrB, bfrA, xS1, xS0)
    }

    // epilogue: C/D layout col=lane, row=quad*4+r
    const int bb = m0 >> 11;
    const int t0 = m0 & 2047;
    __syncthreads();
    #pragma unroll
    for (int ct = 0; ct < 3; ++ct) {
        int c0 = wave * 48 + ct * 16;
        if (c0 < 64) {                          // q: pre-scaled by SCALE2
            int h = c0 + lane;
            #pragma unroll
            for (int rt = 0; rt < 4; ++rt)
                #pragma unroll
                for (int r = 0; r < 4; ++r)
                    qb[(size_t)(m0 + rt * 16 + quad * 4 + r) * HH_ + h] = (bf16)(acc[rt][ct][r] * SCALE2);
        } else if (c0 < 128) {                  // k
            int h = (c0 - 64) + lane;
            #pragma unroll
            for (int rt = 0; rt < 4; ++rt)
                #pragma unroll
                for (int r = 0; r < 4; ++r)
                    kb[(size_t)(m0 + rt * 16 + quad * 4 + r) * HH_ + h] = (bf16)acc[rt][ct][r];
        } else {                                // v -> LDS for transpose
            int h = (c0 - 128) + lane;
            #pragma unroll
            for (int rt = 0; rt < 4; ++rt)
                #pragma unroll
                for (int r = 0; r < 4; ++r)
                    Xs[0][(rt * 16 + quad * 4 + r) * 72 + h] = (bf16)acc[rt][ct][r];
        }
    }
    __syncthreads();
    {
        int h  = tid >> 2;
        int tc = (tid & 3) * 16;
        bf16x8 v0, v1;
        #pragma unroll
        for (int i = 0; i < 8; ++i) v0[i] = Xs[0][(tc + i) * 72 + h];
        #pragma unroll
        for (int i = 0; i < 8; ++i) v1[i] = Xs[0][(tc + 8 + i) * 72 + h];
        bf16* dst = &vt[(size_t)bb * HH_ * TT_ + (size_t)h * TT_ + t0 + tc];
        *(bf16x8*)dst = v0;
        *(bf16x8*)(dst + 8) = v1;
    }
}

// ---------------- flash attention, non-split, direct output ------------------
// Round 13: occupancy isolation. 512-thread blocks = 4 q-waves x 2 k-groups
// (kg handles windows {kg, kg+2}); staging shared; r12's single-barrier LDS
// double-buffer kept. Grid 512 -> 2 blocks/CU -> 16 waves/CU (4/SIMD), 2x
// the independent latency chains per SIMD at identical global traffic.
// Cross-kg combine reuses Ks as fp32 buffer (r6's proven epilogue).
// __launch_bounds__(512,4) caps VGPR at 128 (live est ~85).
__global__ __launch_bounds__(512, 4) void attn_kernel(const bf16* __restrict__ qb,
                                                      const bf16* __restrict__ kb,
                                                      const bf16* __restrict__ vt,
                                                      float* __restrict__ out) {
    __shared__ __align__(16) bf16 Ks[2][128 * 72];
    __shared__ __align__(16) bf16 Vs[2][64 * 136];

    const int tid  = threadIdx.x;
    const int wave = tid >> 6;        // 0..7
    const int qw   = wave & 3;        // q-wave
    const int kg   = wave >> 2;       // k-group
    const int lane = tid & 15;
    const int quad = (tid & 63) >> 4;

    const int j  = blockIdx.x;
    const int bb = j & 15;
    const int p  = j >> 4;
    const int qi = (p < 16) ? p : 47 - p;
    const int nch = (qi >> 1) + 1;          // chunks of 128 keys, incl. diag

    const int qrow  = qi * 64 + qw * 16;
    const int qg    = qrow + lane;          // this lane's q row
    const int qmaxw = qrow + 15;            // max q row in this wave

    // staging (512 threads): K 128x64 rows (krow, krow+64); V^T 64x128 (vh, vh+32)
    const int krow = tid >> 3, kc8 = (tid & 7) * 8;
    const int vh   = tid >> 4, vc8 = (tid & 15) * 8;
    const bf16* kp = kb + (size_t)(bb * TT_ + krow) * HH_ + kc8;
    const bf16* vp = vt + (size_t)bb * HH_ * TT_ + (size_t)vh * TT_ + vc8;

    // prologue: chunk-0 into buf 0
    bf16x8 kr[2], vvr[2];
    #pragma unroll
    for (int j2 = 0; j2 < 2; ++j2) kr[j2]  = *(const bf16x8*)&kp[(size_t)j2 * 64 * HH_];
    #pragma unroll
    for (int j2 = 0; j2 < 2; ++j2) vvr[j2] = *(const bf16x8*)&vp[j2 * 32 * TT_];
    #pragma unroll
    for (int j2 = 0; j2 < 2; ++j2) *(bf16x8*)&Ks[0][(krow + 64 * j2) * 72 + kc8] = kr[j2];
    #pragma unroll
    for (int j2 = 0; j2 < 2; ++j2) *(bf16x8*)&Vs[0][(vh + 32 * j2) * 136 + vc8]  = vvr[j2];
    __syncthreads();

    // Q fragment (B operand): lane -> q col, quad*8 -> h  (pre-scaled)
    bf16x8 aq[2];
    #pragma unroll
    for (int step = 0; step < 2; ++step)
        aq[step] = *(const bf16x8*)&qb[(size_t)(bb * TT_ + qg) * HH_ + step * 32 + quad * 8];

    // all-ones B fragment for the row-sum MFMA
    bf16x8 vones;
    #pragma unroll
    for (int i = 0; i < 8; ++i) vones[i] = (bf16)1.0f;

    f32x4 o_acc[4];
    #pragma unroll
    for (int ht = 0; ht < 4; ++ht) o_acc[ht] = f32x4{0.f, 0.f, 0.f, 0.f};
    f32x4 lacc = f32x4{0.f, 0.f, 0.f, 0.f};

    for (int c = 0; c < nch; ++c) {
        const int s0  = c * 128;
        const int cur = c & 1;
        // issue next chunk's loads first -- in flight across all of compute
        if (c + 1 < nch) {
            #pragma unroll
            for (int j2 = 0; j2 < 2; ++j2)
                kr[j2] = *(const bf16x8*)&kp[(size_t)((c + 1) * 128 + j2 * 64) * HH_];
            #pragma unroll
            for (int j2 = 0; j2 < 2; ++j2)
                vvr[j2] = *(const bf16x8*)&vp[(c + 1) * 128 + j2 * 32 * TT_];
        }

        const bool msk = (c == nch - 1);
        #pragma unroll
        for (int wi = 0; wi < 2; ++wi) {    // this k-group's 2 windows
            const int w = kg + wi * 2;
            if (msk && (s0 + w * 32 > qmaxw)) continue;       // wave-uniform
            const bool haveB = !msk || (s0 + w * 32 + 16 <= qmaxw);

            // QK^T (swapped): s[key=tile+quad*4+r][q=qg]
            f32x4 sA = {0.f, 0.f, 0.f, 0.f};
            f32x4 sB = {0.f, 0.f, 0.f, 0.f};
            __builtin_amdgcn_s_setprio(1);
            {
                bf16x8 ak0 = *(const bf16x8*)&Ks[cur][(w * 32 + lane) * 72 + quad * 8];
                bf16x8 ak1 = *(const bf16x8*)&Ks[cur][(w * 32 + lane) * 72 + 32 + quad * 8];
                sA = __builtin_amdgcn_mfma_f32_16x16x32_bf16(ak0, aq[0], sA, 0, 0, 0);
                sA = __builtin_amdgcn_mfma_f32_16x16x32_bf16(ak1, aq[1], sA, 0, 0, 0);
            }
            if (haveB) {
                bf16x8 bk0 = *(const bf16x8*)&Ks[cur][(w * 32 + 16 + lane) * 72 + quad * 8];
                bf16x8 bk1 = *(const bf16x8*)&Ks[cur][(w * 32 + 16 + lane) * 72 + 32 + quad * 8];
                sB = __builtin_amdgcn_mfma_f32_16x16x32_bf16(bk0, aq[0], sB, 0, 0, 0);
                sB = __builtin_amdgcn_mfma_f32_16x16x32_bf16(bk1, aq[1], sB, 0, 0, 0);
            }
            __builtin_amdgcn_s_setprio(0);

            // softmax (in-register, max-free; scale pre-folded into q)
            const int kA0 = s0 + w * 32 + quad * 4;
            float eA[4], eB[4];
            #pragma unroll
            for (int r = 0; r < 4; ++r) {
                float e = __builtin_amdgcn_exp2f(sA[r]);
                if (msk && (kA0 + r > qg)) e = 0.f;
                eA[r] = e;
            }
            if (haveB) {
                #pragma unroll
                for (int r = 0; r < 4; ++r) {
                    float e = __builtin_amdgcn_exp2f(sB[r]);
                    if (msk && (kA0 + 16 + r > qg)) e = 0.f;
                    eB[r] = e;
                }
            } else {
                #pragma unroll
                for (int r = 0; r < 4; ++r) eB[r] = 0.f;
            }

            // P: C-layout -> 16x16x32 A-layout, all in registers
            unsigned d0 = pack_bf16(eA[0], eA[1]);
            unsigned d1 = pack_bf16(eA[2], eA[3]);
            unsigned d2 = pack_bf16(eB[0], eB[1]);
            unsigned d3 = pack_bf16(eB[2], eB[3]);
            plswap32(d0, d2);
            plswap16(d0, d2);
            plswap32(d1, d3);
            plswap16(d1, d3);
            union { unsigned u[4]; bf16x8 v; } apu;
            apu.u[0] = d0; apu.u[1] = d1; apu.u[2] = d2; apu.u[3] = d3;

            // PV + row-sum: x32 MFMA straight from registers + Vs
            __builtin_amdgcn_s_setprio(1);
            #pragma unroll
            for (int ht = 0; ht < 4; ++ht) {
                bf16x8 bv = *(const bf16x8*)&Vs[cur][(ht * 16 + lane) * 136 + w * 32 + quad * 8];
                o_acc[ht] = __builtin_amdgcn_mfma_f32_16x16x32_bf16(apu.v, bv, o_acc[ht], 0, 0, 0);
            }
            lacc = __builtin_amdgcn_mfma_f32_16x16x32_bf16(apu.v, vones, lacc, 0, 0, 0);
            __builtin_amdgcn_s_setprio(0);
        }

        // write next chunk into the other buffer; ONE barrier per chunk
        if (c + 1 < nch) {
            #pragma unroll
            for (int j2 = 0; j2 < 2; ++j2) *(bf16x8*)&Ks[cur ^ 1][(krow + 64 * j2) * 72 + kc8] = kr[j2];
            #pragma unroll
            for (int j2 = 0; j2 < 2; ++j2) *(bf16x8*)&Vs[cur ^ 1][(vh + 32 * j2) * 136 + vc8]  = vvr[j2];
            __syncthreads();
        }
    }

    // ---- cross-k-group combine (reuse Ks as fp32 buffer, stride 65) ----
    __syncthreads();
    float* cbuf = (float*)&Ks[0][0];      // [64][65] fp32 = 16.6 KB
    float* lbuf = cbuf + 64 * 65;         // 64 fp32
    if (kg == 1) {
        #pragma unroll
        for (int ht = 0; ht < 4; ++ht)
            #pragma unroll
            for (int r = 0; r < 4; ++r)
                cbuf[(qw * 16 + quad * 4 + r) * 65 + ht * 16 + lane] = o_acc[ht][r];
        if (lane == 0) {
            #pragma unroll
            for (int r = 0; r < 4; ++r) lbuf[qw * 16 + quad * 4 + r] = lacc[r];
        }
    }
    __syncthreads();
    if (kg == 0) {
        #pragma unroll
        for (int ht = 0; ht < 4; ++ht)
            #pragma unroll
            for (int r = 0; r < 4; ++r)
                o_acc[ht][r] += cbuf[(qw * 16 + quad * 4 + r) * 65 + ht * 16 + lane];
        float inv[4];
        #pragma unroll
        for (int r = 0; r < 4; ++r)
            inv[r] = __builtin_amdgcn_rcpf(lacc[r] + lbuf[qw * 16 + quad * 4 + r]);
        #pragma unroll
        for (int ht = 0; ht < 4; ++ht)
            #pragma unroll
            for (int r = 0; r < 4; ++r)
                out[(size_t)(bb * TT_ + qrow + quad * 4 + r) * HH_ + ht * 16 + lane] = o_acc[ht][r] * inv[r];
    }
}

extern "C" void kernel_launch(void* const* d_in, const int* in_sizes, int n_in,
                              void* d_out, int out_size, void* d_ws, size_t ws_size,
                              hipStream_t stream) {
    const float* x  = (const float*)d_in[0];
    const float* Wq = (const float*)d_in[1];
    const float* Wk = (const float*)d_in[2];
    const float* Wv = (const float*)d_in[3];
    float* out = (float*)d_out;

    char* ws = (char*)d_ws;
    bf16*  qb = (bf16*)(ws);                       // 4 MiB (pre-scaled q)
    bf16*  kb = (bf16*)(ws + 4194304);             // 4 MiB
    bf16*  vt = (bf16*)(ws + 8388608);             // 4 MiB  V^T [bb][h][t]
    bf16*  Wt = (bf16*)(ws + 12582912);            // 384 KiB

    prep_w<<<48, 256, 0, stream>>>(Wq, Wk, Wv, Wt);
    qkv_kernel<<<512, 256, 0, stream>>>(x, Wt, qb, kb, vt);
    attn_kernel<<<512, 512, 0, stream>>>(qb, kb, vt, out);
}